// Round 12
// baseline (301.640 us; speedup 1.0000x reference)
//
#include <hip/hip_runtime.h>

#define N_NODES 100000
#define N_EDGES 1600000
#define D 128

#define NPAD  48                  // padded per-node slots (Poisson(16), 8 sigma)
#define SB    ((N_EDGES + 255) / 256)           // 6250 scatter blocks

// bucket-padded fallback params (round-9-verified)
#define NCB   512
#define BR    196
#define CHUNK 2048
#define SLOTS 8
#define CAPR  4096
#define PBK   ((N_EDGES + CHUNK - 1) / CHUNK)   // 782

#define XQ   (N_NODES * D / 4)    // x float4 quads = 3,200,000
#define XQB  (XQ / 256)           // 12500 blocks (exact)
#define WQ   (D * D / 4)          // 4096
#define WQB  (WQ / 256)           // 16 blocks (exact)

typedef __bf16 bf16x8 __attribute__((ext_vector_type(8)));
typedef float  f32x4  __attribute__((ext_vector_type(4)));
typedef unsigned short u16x8 __attribute__((ext_vector_type(8)));

static __device__ __forceinline__ unsigned short f2bf(float f) {
    union { float f; unsigned u; } v; v.f = f;
    unsigned r = v.u + 0x7FFFu + ((v.u >> 16) & 1u);   // RNE
    return (unsigned short)(r >> 16);
}

// Accumulate one gathered bf16x8 row (as float4 bits) scaled by wt.
static __device__ __forceinline__ void accum_row(
    float4& acc0, float4& acc1, const float4 u, const float wt)
{
    const unsigned qx = __float_as_uint(u.x);
    const unsigned qy = __float_as_uint(u.y);
    const unsigned qz = __float_as_uint(u.z);
    const unsigned qw = __float_as_uint(u.w);
    acc0.x += wt * __uint_as_float(qx << 16);
    acc0.y += wt * __uint_as_float(qx & 0xFFFF0000u);
    acc0.z += wt * __uint_as_float(qy << 16);
    acc0.w += wt * __uint_as_float(qy & 0xFFFF0000u);
    acc1.x += wt * __uint_as_float(qz << 16);
    acc1.y += wt * __uint_as_float(qz & 0xFFFF0000u);
    acc1.z += wt * __uint_as_float(qw << 16);
    acc1.w += wt * __uint_as_float(qw & 0xFFFF0000u);
}

// ===========================================================================
// PRIMARY (per-node padded) PATH: memset(cur) -> k_sc -> k_gxn.
// Node n owns part[n*NPAD .. n*NPAD+NPAD); scatter via per-node cursors
// (1.6M atomics over 100K L2-resident counters — r4-proven). No histogram,
// no scan, no sort: the sort kernel's ~26MB traffic + 1 dispatch vanish.
// ===========================================================================

// ---------------------------------------------------------------------------
// k_sc: fused edge scatter | x->bf16 cast | W->bf16 cast.
// Scatter blocks FIRST; cast blocks stream behind them.
// ---------------------------------------------------------------------------
__global__ __launch_bounds__(256) void k_sc(
    const float4* __restrict__ x4, ushort4* __restrict__ xh4,
    const float4* __restrict__ w4, ushort4* __restrict__ wh4,
    const int* __restrict__ ei, const float* __restrict__ ew,
    int* __restrict__ cur, int2* __restrict__ part)
{
    const int b = blockIdx.x;
    const int t = threadIdx.x;
    if (b < SB) {
        const int e = b * 256 + t;
        if (e < N_EDGES) {
            const int src = ei[e];
            const int dst = ei[N_EDGES + e];
            const int pos = atomicAdd(&cur[dst], 1);
            if (pos < NPAD)   // 8-sigma guard; protects heap
                part[dst * NPAD + pos] = make_int2(src, __float_as_int(ew[e]));
        }
    } else if (b < SB + XQB) {
        const int i = (b - SB) * 256 + t;
        const float4 v = x4[i];
        xh4[i] = make_ushort4(f2bf(v.x), f2bf(v.y), f2bf(v.z), f2bf(v.w));
    } else {
        const int i = (b - SB - XQB) * 256 + t;
        const float4 v = w4[i];
        wh4[i] = make_ushort4(f2bf(v.x), f2bf(v.y), f2bf(v.z), f2bf(v.w));
    }
}

// ---------------------------------------------------------------------------
// k_gxn: fused gather + MFMA transform, per-node padded edge lists.
// Identical structure to the 76-us round-9/11 k_gx (4-deep gather, VGPR 32,
// 16 groups x 16 lanes, group g owns node m0+g); addressing differs only in
// beg = n*NPAD, end = beg + min(cur[n], NPAD).
// Layouts (verified m89/m91): A[m=lane&15][k=quad*8+j], B[n=lane&15][k=...],
// C: col=lane&15, row=quad*4+reg.
// ---------------------------------------------------------------------------
__global__ __launch_bounds__(256) void k_gxn(
    const float4* __restrict__ xh4,        // bf16 x rows viewed as float4 (8 bf16)
    const int* __restrict__ cur,           // per-node edge counts
    const int2* __restrict__ pair,         // padded per-node {src, w}
    const unsigned short* __restrict__ wh, // bf16 W [n][k]
    const float* __restrict__ bias, const float* __restrict__ pa,
    float* __restrict__ out)
{
    __shared__ unsigned short tb[16][136]; // bf16 tile, stride 272B

    const int tid = threadIdx.x;
    const int g   = tid >> 4;              // 0..15: which node of the tile
    const int sl  = tid & 15;              // feature chunk: 8 bf16 at 8*sl
    const int m0  = blockIdx.x << 4;
    const float aP = pa[0];

    // ---- gather: group g streams node (m0+g)'s edge list ----
    {
        const int n = m0 + g;
        const int beg = n * NPAD;
        const int end = beg + min(cur[n], NPAD);
        float4 acc0 = make_float4(0.f, 0.f, 0.f, 0.f);
        float4 acc1 = make_float4(0.f, 0.f, 0.f, 0.f);

        int e = beg;
        for (; e + 3 < end; e += 4) {
            const int2 p0 = pair[e + 0], p1 = pair[e + 1];
            const int2 p2 = pair[e + 2], p3 = pair[e + 3];
            const float4 u0 = xh4[p0.x * 16 + sl];
            const float4 u1 = xh4[p1.x * 16 + sl];
            const float4 u2 = xh4[p2.x * 16 + sl];
            const float4 u3 = xh4[p3.x * 16 + sl];
            accum_row(acc0, acc1, u0, __int_as_float(p0.y));
            accum_row(acc0, acc1, u1, __int_as_float(p1.y));
            accum_row(acc0, acc1, u2, __int_as_float(p2.y));
            accum_row(acc0, acc1, u3, __int_as_float(p3.y));
        }
        for (; e < end; ++e) {
            const int2 p = pair[e];
            const float4 u = xh4[p.x * 16 + sl];
            accum_row(acc0, acc1, u, __int_as_float(p.y));
        }

        u16x8 s;
        s[0] = f2bf(acc0.x); s[1] = f2bf(acc0.y);
        s[2] = f2bf(acc0.z); s[3] = f2bf(acc0.w);
        s[4] = f2bf(acc1.x); s[5] = f2bf(acc1.y);
        s[6] = f2bf(acc1.z); s[7] = f2bf(acc1.w);
        *(u16x8*)&tb[g][sl * 8] = s;       // features 8sl..8sl+7, 16B aligned
    }
    __syncthreads();

    // ---- MFMA transform on the 16-row bf16 tile ----
    const int lane = tid & 63;
    const int wv = tid >> 6;
    const int mm = lane & 15;
    const int quad = lane >> 4;

    bf16x8 af[4];
    #pragma unroll
    for (int c = 0; c < 4; ++c)
        af[c] = *(const bf16x8*)&tb[mm][c * 32 + quad * 8];

    #pragma unroll
    for (int t = 0; t < 2; ++t) {
        const int n = ((wv * 2 + t) << 4) + mm;
        f32x4 acc = {0.f, 0.f, 0.f, 0.f};
        #pragma unroll
        for (int c = 0; c < 4; ++c) {
            const bf16x8 bf = *(const bf16x8*)(wh + n * D + c * 32 + quad * 8);
            acc = __builtin_amdgcn_mfma_f32_16x16x32_bf16(af[c], bf, acc, 0, 0, 0);
        }
        const float bv = bias[n];
        #pragma unroll
        for (int r = 0; r < 4; ++r) {
            float v = acc[r] + bv;
            v = (v >= 0.f) ? v : aP * v;
            v = fmaxf(v, 0.f);
            out[(size_t)(m0 + (quad << 2) + r) * D + n] = v;
        }
    }
}

// ===========================================================================
// FALLBACK TIER B (bucket-padded, round-9/11-verified at 230.7us):
// memset(gcur) -> k_pc -> k_csrp -> k_gx.
// ===========================================================================
__global__ __launch_bounds__(256) void k_pc(
    const float4* __restrict__ x4, ushort4* __restrict__ xh4,
    const float4* __restrict__ w4, ushort4* __restrict__ wh4,
    const int* __restrict__ ei, const float* __restrict__ ew,
    int* __restrict__ gcur, int2* __restrict__ part)
{
    __shared__ int2 bins[NCB * SLOTS];   // 32 KB
    __shared__ int bcnt[NCB];
    __shared__ int bbase[NCB];
    const int b = blockIdx.x;
    const int t = threadIdx.x;

    if (b < PBK) {
        bcnt[t] = 0; bcnt[t + 256] = 0;
        __syncthreads();
        const int e0 = b * CHUNK;
        #pragma unroll 8
        for (int k = 0; k < CHUNK / 256; ++k) {
            const int e = e0 + k * 256 + t;
            if (e < N_EDGES) {
                const int dst = ei[N_EDGES + e];
                const int src = ei[e];
                const int bk = dst / BR;
                const int ld = dst - bk * BR;
                const int2 p = make_int2(src | (ld << 17), __float_as_int(ew[e]));
                const int r = atomicAdd(&bcnt[bk], 1);
                if (r < SLOTS) bins[bk * SLOTS + r] = p;
                else {
                    const int pos = atomicAdd(&gcur[bk], 1);
                    if (pos < CAPR) part[bk * CAPR + pos] = p;
                }
            }
        }
        __syncthreads();
        {
            const int c0 = min(bcnt[t], SLOTS);
            const int c1 = min(bcnt[t + 256], SLOTS);
            bbase[t]       = c0 ? atomicAdd(&gcur[t], c0) : 0;
            bbase[t + 256] = c1 ? atomicAdd(&gcur[t + 256], c1) : 0;
            bcnt[t] = c0; bcnt[t + 256] = c1;
        }
        __syncthreads();
        for (int s = t; s < NCB * SLOTS; s += 256) {
            const int bk = s >> 3;
            const int r = s & 7;
            if (r < bcnt[bk]) {
                const int pos = bbase[bk] + r;
                if (pos < CAPR) part[bk * CAPR + pos] = bins[s];
            }
        }
    } else if (b < PBK + XQB) {
        const int i = (b - PBK) * 256 + t;
        const float4 v = x4[i];
        xh4[i] = make_ushort4(f2bf(v.x), f2bf(v.y), f2bf(v.z), f2bf(v.w));
    } else {
        const int i = (b - PBK - XQB) * 256 + t;
        const float4 v = w4[i];
        wh4[i] = make_ushort4(f2bf(v.x), f2bf(v.y), f2bf(v.z), f2bf(v.w));
    }
}

__global__ __launch_bounds__(256) void k_csrp(
    const int* __restrict__ gcur, int2* __restrict__ part, int2* __restrict__ off2)
{
    __shared__ int2 buf[CAPR];   // 32 KB
    __shared__ int nh[256];
    __shared__ int orig[256];
    __shared__ int cur[256];

    const int b = blockIdx.x;
    const int t = threadIdx.x;
    const int lo = b * BR;
    const int base = b * CAPR;
    int cnt = gcur[b];
    if (cnt > CAPR) cnt = CAPR;

    nh[t] = 0;
    __syncthreads();

    for (int i = t; i < cnt; i += 256) {
        const int2 p = part[base + i];
        buf[i] = p;
        atomicAdd(&nh[((unsigned)p.x) >> 17], 1);
    }
    __syncthreads();
    orig[t] = nh[t];
    __syncthreads();
    for (int d = 1; d < 256; d <<= 1) {
        const int u = (t >= d) ? nh[t - d] : 0;
        __syncthreads();
        nh[t] += u;
        __syncthreads();
    }
    const int excl = nh[t] - orig[t];
    cur[t] = excl;
    if (t < BR && lo + t < N_NODES)
        off2[lo + t] = make_int2(base + excl, base + excl + orig[t]);
    __syncthreads();

    for (int i = t; i < cnt; i += 256) {
        const int2 p = buf[i];
        const int ld = ((unsigned)p.x) >> 17;
        const int r = atomicAdd(&cur[ld], 1);
        part[base + r] = make_int2(p.x & 0x1FFFF, p.y);
    }
}

__global__ __launch_bounds__(256) void k_gx(
    const float4* __restrict__ xh4,
    const int2* __restrict__ off2,
    const int2* __restrict__ pair,
    const unsigned short* __restrict__ wh,
    const float* __restrict__ bias, const float* __restrict__ pa,
    float* __restrict__ out)
{
    __shared__ unsigned short tb[16][136];

    const int tid = threadIdx.x;
    const int g   = tid >> 4;
    const int sl  = tid & 15;
    const int m0  = blockIdx.x << 4;
    const float aP = pa[0];

    {
        const int2 oo = off2[m0 + g];
        const int end = oo.y;
        float4 acc0 = make_float4(0.f, 0.f, 0.f, 0.f);
        float4 acc1 = make_float4(0.f, 0.f, 0.f, 0.f);

        int e = oo.x;
        for (; e + 3 < end; e += 4) {
            const int2 p0 = pair[e + 0], p1 = pair[e + 1];
            const int2 p2 = pair[e + 2], p3 = pair[e + 3];
            const float4 u0 = xh4[p0.x * 16 + sl];
            const float4 u1 = xh4[p1.x * 16 + sl];
            const float4 u2 = xh4[p2.x * 16 + sl];
            const float4 u3 = xh4[p3.x * 16 + sl];
            accum_row(acc0, acc1, u0, __int_as_float(p0.y));
            accum_row(acc0, acc1, u1, __int_as_float(p1.y));
            accum_row(acc0, acc1, u2, __int_as_float(p2.y));
            accum_row(acc0, acc1, u3, __int_as_float(p3.y));
        }
        for (; e < end; ++e) {
            const int2 p = pair[e];
            const float4 u = xh4[p.x * 16 + sl];
            accum_row(acc0, acc1, u, __int_as_float(p.y));
        }

        u16x8 s;
        s[0] = f2bf(acc0.x); s[1] = f2bf(acc0.y);
        s[2] = f2bf(acc0.z); s[3] = f2bf(acc0.w);
        s[4] = f2bf(acc1.x); s[5] = f2bf(acc1.y);
        s[6] = f2bf(acc1.z); s[7] = f2bf(acc1.w);
        *(u16x8*)&tb[g][sl * 8] = s;
    }
    __syncthreads();

    const int lane = tid & 63;
    const int wv = tid >> 6;
    const int mm = lane & 15;
    const int quad = lane >> 4;

    bf16x8 af[4];
    #pragma unroll
    for (int c = 0; c < 4; ++c)
        af[c] = *(const bf16x8*)&tb[mm][c * 32 + quad * 8];

    #pragma unroll
    for (int t = 0; t < 2; ++t) {
        const int n = ((wv * 2 + t) << 4) + mm;
        f32x4 acc = {0.f, 0.f, 0.f, 0.f};
        #pragma unroll
        for (int c = 0; c < 4; ++c) {
            const bf16x8 bf = *(const bf16x8*)(wh + n * D + c * 32 + quad * 8);
            acc = __builtin_amdgcn_mfma_f32_16x16x32_bf16(af[c], bf, acc, 0, 0, 0);
        }
        const float bv = bias[n];
        #pragma unroll
        for (int r = 0; r < 4; ++r) {
            float v = acc[r] + bv;
            v = (v >= 0.f) ? v : aP * v;
            v = fmaxf(v, 0.f);
            out[(size_t)(m0 + (quad << 2) + r) * D + n] = v;
        }
    }
}

// ---------------------------------------------------------------------------
// Tier-C fallbacks (tiny ws): atomic scatter + fp32 vector transform.
// ---------------------------------------------------------------------------
__global__ __launch_bounds__(256) void gcn_scatter(
    const float* __restrict__ x, const int* __restrict__ ei,
    const float* __restrict__ ew, float* __restrict__ agg)
{
    const int lane = threadIdx.x & 63;
    const int wave = (blockIdx.x * blockDim.x + threadIdx.x) >> 6;
    const int nwaves = (gridDim.x * blockDim.x) >> 6;
    for (int e = wave; e < N_EDGES; e += nwaves) {
        const int src = ei[e];
        const int dst = ei[N_EDGES + e];
        const float w = ew[e];
        const float2 v = ((const float2*)(x + (size_t)src * D))[lane];
        float* op = agg + (size_t)dst * D + lane * 2;
        unsafeAtomicAdd(op,     w * v.x);
        unsafeAtomicAdd(op + 1, w * v.y);
    }
}

#define MT 32
__global__ __launch_bounds__(256, 2) void gcn_transform(
    const float* __restrict__ A, const float* __restrict__ W,
    const float* __restrict__ bias, const float* __restrict__ pa,
    float* __restrict__ out)
{
    __shared__ float Wt[D][D];
    __shared__ float xs[MT][D];
    const int tid = threadIdx.x;
    const int row0 = blockIdx.x * MT;

    for (int j = tid; j < D * (D / 4); j += 256) {
        const int n = j & 127;
        const int kg = j >> 7;
        const float4 v = ((const float4*)W)[n * (D / 4) + kg];
        const int k4 = kg << 2;
        Wt[k4 + 0][n] = v.x; Wt[k4 + 1][n] = v.y;
        Wt[k4 + 2][n] = v.z; Wt[k4 + 3][n] = v.w;
    }
    for (int i = tid; i < MT * (D / 4); i += 256) {
        const int r = i >> 5;
        const int c4 = i & 31;
        ((float4*)xs[r])[c4] = ((const float4*)(A + (size_t)(row0 + r) * D))[c4];
    }
    __syncthreads();

    const int tn = tid & 31;
    const int tm = tid >> 5;
    float acc[4][4] = {};
    #pragma unroll
    for (int k = 0; k < D; k += 4) {
        const float4 wv0 = *(const float4*)&Wt[k + 0][tn * 4];
        const float4 wv1 = *(const float4*)&Wt[k + 1][tn * 4];
        const float4 wv2 = *(const float4*)&Wt[k + 2][tn * 4];
        const float4 wv3 = *(const float4*)&Wt[k + 3][tn * 4];
        #pragma unroll
        for (int i = 0; i < 4; ++i) {
            const float4 xv = *(const float4*)&xs[tm * 4 + i][k];
            acc[i][0] += xv.x * wv0.x + xv.y * wv1.x + xv.z * wv2.x + xv.w * wv3.x;
            acc[i][1] += xv.x * wv0.y + xv.y * wv1.y + xv.z * wv2.y + xv.w * wv3.y;
            acc[i][2] += xv.x * wv0.z + xv.y * wv1.z + xv.z * wv2.z + xv.w * wv3.z;
            acc[i][3] += xv.x * wv0.w + xv.y * wv1.w + xv.z * wv2.w + xv.w * wv3.w;
        }
    }
    const float a = pa[0];
    const float4 bv = ((const float4*)bias)[tn];
    #pragma unroll
    for (int i = 0; i < 4; ++i) {
        const int gr = row0 + tm * 4 + i;
        float t0 = acc[i][0] + bv.x, t1 = acc[i][1] + bv.y;
        float t2 = acc[i][2] + bv.z, t3 = acc[i][3] + bv.w;
        float4 r;
        r.x = fmaxf(t0 >= 0.f ? t0 : a * t0, 0.f);
        r.y = fmaxf(t1 >= 0.f ? t1 : a * t1, 0.f);
        r.z = fmaxf(t2 >= 0.f ? t2 : a * t2, 0.f);
        r.w = fmaxf(t3 >= 0.f ? t3 : a * t3, 0.f);
        ((float4*)(out + (size_t)gr * D))[tn] = r;
    }
}

// ---------------------------------------------------------------------------
extern "C" void kernel_launch(void* const* d_in, const int* in_sizes, int n_in,
                              void* d_out, int out_size, void* d_ws, size_t ws_size,
                              hipStream_t stream) {
    const float* x    = (const float*)d_in[0];
    const int*   ei   = (const int*)d_in[1];
    const float* ew   = (const float*)d_in[2];
    const float* W    = (const float*)d_in[3];
    const float* bias = (const float*)d_in[4];
    const float* pa   = (const float*)d_in[5];
    float* out = (float*)d_out;
    int* wsb = (int*)d_ws;

    // ---- per-node padded layout (int units) ----
    const size_t n_cur  = 0;                                  // N_NODES
    const size_t n_part = 100000;                             // even -> int2 ok
    const size_t n_wh   = n_part + 2 * (size_t)N_NODES * NPAD; // 9,700,000 (%4==0)
    const size_t n_xh   = n_wh + (size_t)D * D / 2;           // 9,708,192 (%4==0)
    const size_t needN  = (n_xh + (size_t)N_NODES * D / 2) * 4;  // ~64.4 MB

    // ---- bucket-padded layout (round-9-verified, int units) ----
    const size_t p_gcur = 0;                                  // 512
    const size_t p_off2 = 512;                                // 2*N_NODES
    const size_t p_part = p_off2 + 2 * (size_t)N_NODES;       // 200512 (even)
    const size_t p_wh   = p_part + 2 * (size_t)NCB * CAPR;    // %4==0
    const size_t p_xh   = p_wh + (size_t)D * D / 2;           // %4==0
    const size_t needP  = (p_xh + (size_t)N_NODES * D / 2) * 4;  // ~43.2 MB

    if (ws_size >= needN) {
        int* cur   = wsb + n_cur;
        int2* part = (int2*)(wsb + n_part);
        unsigned short* wh = (unsigned short*)(wsb + n_wh);
        unsigned short* xh = (unsigned short*)(wsb + n_xh);

        (void)hipMemsetAsync(cur, 0, N_NODES * sizeof(int), stream);
        k_sc  <<<SB + XQB + WQB, 256, 0, stream>>>(
            (const float4*)x, (ushort4*)xh, (const float4*)W, (ushort4*)wh,
            ei, ew, cur, part);
        k_gxn <<<N_NODES / 16, 256, 0, stream>>>(
            (const float4*)xh, cur, part, wh, bias, pa, out);
    } else if (ws_size >= needP) {
        int* gcur  = wsb + p_gcur;
        int2* off2 = (int2*)(wsb + p_off2);
        int2* part = (int2*)(wsb + p_part);
        unsigned short* wh = (unsigned short*)(wsb + p_wh);
        unsigned short* xh = (unsigned short*)(wsb + p_xh);

        (void)hipMemsetAsync(gcur, 0, NCB * sizeof(int), stream);
        k_pc  <<<PBK + XQB + WQB, 256, 0, stream>>>(
            (const float4*)x, (ushort4*)xh, (const float4*)W, (ushort4*)wh,
            ei, ew, gcur, part);
        k_csrp<<<NCB, 256, 0, stream>>>(gcur, part, off2);
        k_gx  <<<N_NODES / 16, 256, 0, stream>>>(
            (const float4*)xh, off2, part, wh, bias, pa, out);
    } else {
        (void)hipMemsetAsync(out, 0, (size_t)N_NODES * D * sizeof(float), stream);
        gcn_scatter<<<12800, 256, 0, stream>>>(x, ei, ew, out);
        gcn_transform<<<N_NODES / MT, 256, 0, stream>>>(out, W, bias, pa, out);
    }
}

// Round 13
// 230.686 us; speedup vs baseline: 1.3076x; 1.3076x over previous
//
#include <hip/hip_runtime.h>

#define N_NODES 100000
#define N_EDGES 1600000
#define D 128

#define NCB   512                 // coarse buckets
#define BR    196                 // nodes per coarse bucket
#define CHUNK 2048                // edges per partition block (782 blocks)
#define SLOTS 8                   // LDS bin capacity (mean fill 4) -> 32KB bins
#define CAPR  4096                // padded per-bucket region (mean 3125, 17 sigma)
#define CAP   4352                // compacted-path LDS sort capacity (fallback)
#define PBK   ((N_EDGES + CHUNK - 1) / CHUNK)   // 782

#define XQ   (N_NODES * D / 4)    // x float4 quads = 3,200,000
#define XQB  (XQ / 256)           // 12500 blocks (exact)
#define WQ   (D * D / 4)          // 4096
#define WQB  (WQ / 256)           // 16 blocks (exact)
#define HB   256                  // histogram blocks (fallback path)

typedef __bf16 bf16x8 __attribute__((ext_vector_type(8)));
typedef float  f32x4  __attribute__((ext_vector_type(4)));
typedef unsigned short u16x8 __attribute__((ext_vector_type(8)));

static __device__ __forceinline__ unsigned short f2bf(float f) {
    union { float f; unsigned u; } v; v.f = f;
    unsigned r = v.u + 0x7FFFu + ((v.u >> 16) & 1u);   // RNE
    return (unsigned short)(r >> 16);
}

// Accumulate one gathered bf16x8 row (as float4 bits) scaled by wt.
static __device__ __forceinline__ void accum_row(
    float4& acc0, float4& acc1, const float4 u, const float wt)
{
    const unsigned qx = __float_as_uint(u.x);
    const unsigned qy = __float_as_uint(u.y);
    const unsigned qz = __float_as_uint(u.z);
    const unsigned qw = __float_as_uint(u.w);
    acc0.x += wt * __uint_as_float(qx << 16);
    acc0.y += wt * __uint_as_float(qx & 0xFFFF0000u);
    acc0.z += wt * __uint_as_float(qy << 16);
    acc0.w += wt * __uint_as_float(qy & 0xFFFF0000u);
    acc1.x += wt * __uint_as_float(qz << 16);
    acc1.y += wt * __uint_as_float(qz & 0xFFFF0000u);
    acc1.z += wt * __uint_as_float(qw << 16);
    acc1.w += wt * __uint_as_float(qw & 0xFFFF0000u);
}

// ===========================================================================
// PRIMARY (bucket-padded) PATH: memset(gcur) -> k_pc -> k_csrp -> k_gx.
// Bucket b owns part[b*CAPR .. b*CAPR+CAPR); no histogram/scan needed.
// k_csrp emits off2[n]={beg,end} so padded gaps are never dereferenced.
// NOTE (r12 lesson): do NOT replace the LDS-binned partition + sort with a
// direct per-node scatter — random 8B writes incur ~10x write amplification
// (WRITE_SIZE 127MB vs 38MB expected; k_sc=130us). The bins exist to turn
// random scatter into contiguous >=64B runs.
// ===========================================================================

// ---------------------------------------------------------------------------
// k_pc: fused edge partition | x->bf16 cast | W->bf16 cast.
// 36KB LDS -> 4 blocks/CU; cast blocks stream behind partition blocks.
// ---------------------------------------------------------------------------
__global__ __launch_bounds__(256) void k_pc(
    const float4* __restrict__ x4, ushort4* __restrict__ xh4,
    const float4* __restrict__ w4, ushort4* __restrict__ wh4,
    const int* __restrict__ ei, const float* __restrict__ ew,
    int* __restrict__ gcur, int2* __restrict__ part)
{
    __shared__ int2 bins[NCB * SLOTS];   // 32 KB
    __shared__ int bcnt[NCB];
    __shared__ int bbase[NCB];
    const int b = blockIdx.x;
    const int t = threadIdx.x;

    if (b < PBK) {
        bcnt[t] = 0; bcnt[t + 256] = 0;
        __syncthreads();
        const int e0 = b * CHUNK;
        #pragma unroll 8
        for (int k = 0; k < CHUNK / 256; ++k) {
            const int e = e0 + k * 256 + t;
            if (e < N_EDGES) {
                const int dst = ei[N_EDGES + e];
                const int src = ei[e];
                const int bk = dst / BR;
                const int ld = dst - bk * BR;
                const int2 p = make_int2(src | (ld << 17), __float_as_int(ew[e]));
                const int r = atomicAdd(&bcnt[bk], 1);
                if (r < SLOTS) bins[bk * SLOTS + r] = p;
                else {
                    const int pos = atomicAdd(&gcur[bk], 1);
                    if (pos < CAPR) part[bk * CAPR + pos] = p;  // guard: heap safety
                }
            }
        }
        __syncthreads();
        {
            const int c0 = min(bcnt[t], SLOTS);
            const int c1 = min(bcnt[t + 256], SLOTS);
            bbase[t]       = c0 ? atomicAdd(&gcur[t], c0) : 0;
            bbase[t + 256] = c1 ? atomicAdd(&gcur[t + 256], c1) : 0;
            bcnt[t] = c0; bcnt[t + 256] = c1;
        }
        __syncthreads();
        for (int s = t; s < NCB * SLOTS; s += 256) {
            const int bk = s >> 3;
            const int r = s & 7;
            if (r < bcnt[bk]) {
                const int pos = bbase[bk] + r;
                if (pos < CAPR) part[bk * CAPR + pos] = bins[s];
            }
        }
    } else if (b < PBK + XQB) {
        const int i = (b - PBK) * 256 + t;
        const float4 v = x4[i];
        xh4[i] = make_ushort4(f2bf(v.x), f2bf(v.y), f2bf(v.z), f2bf(v.w));
    } else {
        const int i = (b - PBK - XQB) * 256 + t;
        const float4 v = w4[i];
        wh4[i] = make_ushort4(f2bf(v.x), f2bf(v.y), f2bf(v.z), f2bf(v.w));
    }
}

// ---------------------------------------------------------------------------
// k_csrp: per-bucket counting sort inside the padded region; emits
// off2[n] = {beg, end} (absolute into part). 32KB LDS -> 4 blocks/CU.
// ---------------------------------------------------------------------------
__global__ __launch_bounds__(256) void k_csrp(
    const int* __restrict__ gcur, int2* __restrict__ part, int2* __restrict__ off2)
{
    __shared__ int2 buf[CAPR];   // 32 KB
    __shared__ int nh[256];
    __shared__ int orig[256];
    __shared__ int cur[256];

    const int b = blockIdx.x;
    const int t = threadIdx.x;
    const int lo = b * BR;
    const int base = b * CAPR;
    int cnt = gcur[b];
    if (cnt > CAPR) cnt = CAPR;  // statistically unreachable; guards LDS

    nh[t] = 0;
    __syncthreads();

    for (int i = t; i < cnt; i += 256) {
        const int2 p = part[base + i];
        buf[i] = p;
        atomicAdd(&nh[((unsigned)p.x) >> 17], 1);
    }
    __syncthreads();
    orig[t] = nh[t];
    __syncthreads();
    for (int d = 1; d < 256; d <<= 1) {
        const int u = (t >= d) ? nh[t - d] : 0;
        __syncthreads();
        nh[t] += u;
        __syncthreads();
    }
    const int excl = nh[t] - orig[t];
    cur[t] = excl;
    if (t < BR && lo + t < N_NODES)
        off2[lo + t] = make_int2(base + excl, base + excl + orig[t]);
    __syncthreads();

    for (int i = t; i < cnt; i += 256) {
        const int2 p = buf[i];
        const int ld = ((unsigned)p.x) >> 17;
        const int r = atomicAdd(&cur[ld], 1);
        part[base + r] = make_int2(p.x & 0x1FFFF, p.y);
    }
}

// ===========================================================================
// FALLBACK (compacted) PATH — round-8-proven chain, off2-emitting.
// ===========================================================================
__global__ __launch_bounds__(256) void k_prep(
    const float4* __restrict__ x4, ushort4* __restrict__ xh4,
    const float4* __restrict__ w4, ushort4* __restrict__ wh4,
    const int* __restrict__ ei, int* __restrict__ ghist)
{
    __shared__ int h[NCB];
    const int b = blockIdx.x;
    const int t = threadIdx.x;
    if (b < HB) {
        h[t] = 0; h[t + 256] = 0;
        __syncthreads();
        for (int e = b * 256 + t; e < N_EDGES; e += HB * 256)
            atomicAdd(&h[ei[N_EDGES + e] / BR], 1);
        __syncthreads();
        atomicAdd(&ghist[t], h[t]);
        atomicAdd(&ghist[t + 256], h[t + 256]);
    } else if (b < HB + XQB) {
        const int i = (b - HB) * 256 + t;
        const float4 v = x4[i];
        xh4[i] = make_ushort4(f2bf(v.x), f2bf(v.y), f2bf(v.z), f2bf(v.w));
    } else {
        const int i = (b - HB - XQB) * 256 + t;
        const float4 v = w4[i];
        wh4[i] = make_ushort4(f2bf(v.x), f2bf(v.y), f2bf(v.z), f2bf(v.w));
    }
}

__global__ __launch_bounds__(512) void k_cscan(
    const int* __restrict__ ghist, int* __restrict__ cOff, int* __restrict__ gcur)
{
    __shared__ int sh[NCB];
    const int t = threadIdx.x;
    const int v = ghist[t];
    sh[t] = v;
    __syncthreads();
    for (int d = 1; d < NCB; d <<= 1) {
        int u = (t >= d) ? sh[t - d] : 0;
        __syncthreads();
        sh[t] += u;
        __syncthreads();
    }
    const int excl = sh[t] - v;
    cOff[t] = excl;
    gcur[t] = excl;
    if (t == NCB - 1) cOff[NCB] = sh[NCB - 1];
}

__global__ __launch_bounds__(256) void k_partc(
    const int* __restrict__ ei, const float* __restrict__ ew,
    int* __restrict__ gcur, int2* __restrict__ part)
{
    __shared__ int2 bins[NCB * SLOTS];   // 32 KB
    __shared__ int bcnt[NCB];
    __shared__ int bbase[NCB];
    const int t = threadIdx.x;
    const int e0 = blockIdx.x * CHUNK;

    bcnt[t] = 0; bcnt[t + 256] = 0;
    __syncthreads();

    #pragma unroll 8
    for (int k = 0; k < CHUNK / 256; ++k) {
        const int e = e0 + k * 256 + t;
        if (e < N_EDGES) {
            const int dst = ei[N_EDGES + e];
            const int src = ei[e];
            const int b = dst / BR;
            const int ld = dst - b * BR;
            const int2 p = make_int2(src | (ld << 17), __float_as_int(ew[e]));
            const int r = atomicAdd(&bcnt[b], 1);
            if (r < SLOTS) bins[b * SLOTS + r] = p;
            else part[atomicAdd(&gcur[b], 1)] = p;
        }
    }
    __syncthreads();

    {
        int c0 = min(bcnt[t], SLOTS);
        int c1 = min(bcnt[t + 256], SLOTS);
        bbase[t]       = c0 ? atomicAdd(&gcur[t], c0) : 0;
        bbase[t + 256] = c1 ? atomicAdd(&gcur[t + 256], c1) : 0;
        bcnt[t] = c0; bcnt[t + 256] = c1;
    }
    __syncthreads();

    for (int s = t; s < NCB * SLOTS; s += 256) {
        const int b = s >> 3;
        const int r = s & 7;
        if (r < bcnt[b]) part[bbase[b] + r] = bins[s];
    }
}

__global__ __launch_bounds__(256) void k_csrc(
    const int* __restrict__ cOff, int2* __restrict__ part, int2* __restrict__ off2)
{
    __shared__ int2 buf[CAP];    // 34 KB
    __shared__ int nh[256];
    __shared__ int orig[256];
    __shared__ int cur[256];

    const int b = blockIdx.x;
    const int t = threadIdx.x;
    const int lo = b * BR;
    const int base = cOff[b];
    int cnt = cOff[b + 1] - base;
    if (cnt > CAP) cnt = CAP;

    nh[t] = 0;
    __syncthreads();

    for (int i = t; i < cnt; i += 256) {
        const int2 p = part[base + i];
        buf[i] = p;
        atomicAdd(&nh[((unsigned)p.x) >> 17], 1);
    }
    __syncthreads();
    orig[t] = nh[t];
    __syncthreads();
    for (int d = 1; d < 256; d <<= 1) {
        int u = (t >= d) ? nh[t - d] : 0;
        __syncthreads();
        nh[t] += u;
        __syncthreads();
    }
    const int excl = nh[t] - orig[t];
    cur[t] = excl;
    if (t < BR && lo + t < N_NODES)
        off2[lo + t] = make_int2(base + excl, base + excl + orig[t]);
    __syncthreads();

    for (int i = t; i < cnt; i += 256) {
        const int2 p = buf[i];
        const int ld = ((unsigned)p.x) >> 17;
        const int r = atomicAdd(&cur[ld], 1);
        part[base + r] = make_int2(p.x & 0x1FFFF, p.y);
    }
}

// ---------------------------------------------------------------------------
// Fused gather + MFMA transform (round-9/11-verified: 4-deep gather, VGPR 32).
// 256 threads = 16 groups of 16 lanes; group g owns node m0+g; all 16 nodes
// progress concurrently; 16 lanes x 16B = full 256B row per issue slot.
// 4 rows in flight/group = 64/block is the measured sweet spot: 8-deep
// (r10) cost occupancy 73->40% and regressed 76->93us; 4-node-serial (r5)
// was 108us. off2[n]={beg,end}: one 8B load, padded-layout-safe.
// Layouts (verified m89/m91): A[m=lane&15][k=quad*8+j], B[n=lane&15][k=...],
// C: col=lane&15, row=quad*4+reg.
// ---------------------------------------------------------------------------
__global__ __launch_bounds__(256) void k_gx(
    const float4* __restrict__ xh4,        // bf16 x rows viewed as float4 (8 bf16)
    const int2* __restrict__ off2,
    const int2* __restrict__ pair,         // CSR {src, w}
    const unsigned short* __restrict__ wh, // bf16 W [n][k]
    const float* __restrict__ bias, const float* __restrict__ pa,
    float* __restrict__ out)
{
    __shared__ unsigned short tb[16][136]; // bf16 tile, stride 272B

    const int tid = threadIdx.x;
    const int g   = tid >> 4;              // 0..15: which node of the tile
    const int sl  = tid & 15;              // feature chunk: 8 bf16 at 8*sl
    const int m0  = blockIdx.x << 4;
    const float aP = pa[0];

    // ---- gather: group g streams node (m0+g)'s edge list ----
    {
        const int2 oo = off2[m0 + g];
        const int end = oo.y;
        float4 acc0 = make_float4(0.f, 0.f, 0.f, 0.f);
        float4 acc1 = make_float4(0.f, 0.f, 0.f, 0.f);

        int e = oo.x;
        for (; e + 3 < end; e += 4) {
            const int2 p0 = pair[e + 0], p1 = pair[e + 1];
            const int2 p2 = pair[e + 2], p3 = pair[e + 3];
            const float4 u0 = xh4[p0.x * 16 + sl];
            const float4 u1 = xh4[p1.x * 16 + sl];
            const float4 u2 = xh4[p2.x * 16 + sl];
            const float4 u3 = xh4[p3.x * 16 + sl];
            accum_row(acc0, acc1, u0, __int_as_float(p0.y));
            accum_row(acc0, acc1, u1, __int_as_float(p1.y));
            accum_row(acc0, acc1, u2, __int_as_float(p2.y));
            accum_row(acc0, acc1, u3, __int_as_float(p3.y));
        }
        for (; e < end; ++e) {
            const int2 p = pair[e];
            const float4 u = xh4[p.x * 16 + sl];
            accum_row(acc0, acc1, u, __int_as_float(p.y));
        }

        u16x8 s;
        s[0] = f2bf(acc0.x); s[1] = f2bf(acc0.y);
        s[2] = f2bf(acc0.z); s[3] = f2bf(acc0.w);
        s[4] = f2bf(acc1.x); s[5] = f2bf(acc1.y);
        s[6] = f2bf(acc1.z); s[7] = f2bf(acc1.w);
        *(u16x8*)&tb[g][sl * 8] = s;       // features 8sl..8sl+7, 16B aligned
    }
    __syncthreads();

    // ---- MFMA transform on the 16-row bf16 tile ----
    const int lane = tid & 63;
    const int wv = tid >> 6;
    const int mm = lane & 15;
    const int quad = lane >> 4;

    bf16x8 af[4];
    #pragma unroll
    for (int c = 0; c < 4; ++c)
        af[c] = *(const bf16x8*)&tb[mm][c * 32 + quad * 8];

    #pragma unroll
    for (int t = 0; t < 2; ++t) {
        const int n = ((wv * 2 + t) << 4) + mm;
        f32x4 acc = {0.f, 0.f, 0.f, 0.f};
        #pragma unroll
        for (int c = 0; c < 4; ++c) {
            const bf16x8 bf = *(const bf16x8*)(wh + n * D + c * 32 + quad * 8);
            acc = __builtin_amdgcn_mfma_f32_16x16x32_bf16(af[c], bf, acc, 0, 0, 0);
        }
        const float bv = bias[n];
        #pragma unroll
        for (int r = 0; r < 4; ++r) {
            float v = acc[r] + bv;
            v = (v >= 0.f) ? v : aP * v;
            v = fmaxf(v, 0.f);
            out[(size_t)(m0 + (quad << 2) + r) * D + n] = v;
        }
    }
}

// ---------------------------------------------------------------------------
// Tier-C fallbacks (tiny ws): atomic scatter + fp32 vector transform.
// ---------------------------------------------------------------------------
__global__ __launch_bounds__(256) void gcn_scatter(
    const float* __restrict__ x, const int* __restrict__ ei,
    const float* __restrict__ ew, float* __restrict__ agg)
{
    const int lane = threadIdx.x & 63;
    const int wave = (blockIdx.x * blockDim.x + threadIdx.x) >> 6;
    const int nwaves = (gridDim.x * blockDim.x) >> 6;
    for (int e = wave; e < N_EDGES; e += nwaves) {
        const int src = ei[e];
        const int dst = ei[N_EDGES + e];
        const float w = ew[e];
        const float2 v = ((const float2*)(x + (size_t)src * D))[lane];
        float* op = agg + (size_t)dst * D + lane * 2;
        unsafeAtomicAdd(op,     w * v.x);
        unsafeAtomicAdd(op + 1, w * v.y);
    }
}

#define MT 32
__global__ __launch_bounds__(256, 2) void gcn_transform(
    const float* __restrict__ A, const float* __restrict__ W,
    const float* __restrict__ bias, const float* __restrict__ pa,
    float* __restrict__ out)
{
    __shared__ float Wt[D][D];
    __shared__ float xs[MT][D];
    const int tid = threadIdx.x;
    const int row0 = blockIdx.x * MT;

    for (int j = tid; j < D * (D / 4); j += 256) {
        const int n = j & 127;
        const int kg = j >> 7;
        const float4 v = ((const float4*)W)[n * (D / 4) + kg];
        const int k4 = kg << 2;
        Wt[k4 + 0][n] = v.x; Wt[k4 + 1][n] = v.y;
        Wt[k4 + 2][n] = v.z; Wt[k4 + 3][n] = v.w;
    }
    for (int i = tid; i < MT * (D / 4); i += 256) {
        const int r = i >> 5;
        const int c4 = i & 31;
        ((float4*)xs[r])[c4] = ((const float4*)(A + (size_t)(row0 + r) * D))[c4];
    }
    __syncthreads();

    const int tn = tid & 31;
    const int tm = tid >> 5;
    float acc[4][4] = {};
    #pragma unroll
    for (int k = 0; k < D; k += 4) {
        const float4 wv0 = *(const float4*)&Wt[k + 0][tn * 4];
        const float4 wv1 = *(const float4*)&Wt[k + 1][tn * 4];
        const float4 wv2 = *(const float4*)&Wt[k + 2][tn * 4];
        const float4 wv3 = *(const float4*)&Wt[k + 3][tn * 4];
        #pragma unroll
        for (int i = 0; i < 4; ++i) {
            const float4 xv = *(const float4*)&xs[tm * 4 + i][k];
            acc[i][0] += xv.x * wv0.x + xv.y * wv1.x + xv.z * wv2.x + xv.w * wv3.x;
            acc[i][1] += xv.x * wv0.y + xv.y * wv1.y + xv.z * wv2.y + xv.w * wv3.y;
            acc[i][2] += xv.x * wv0.z + xv.y * wv1.z + xv.z * wv2.z + xv.w * wv3.z;
            acc[i][3] += xv.x * wv0.w + xv.y * wv1.w + xv.z * wv2.w + xv.w * wv3.w;
        }
    }
    const float a = pa[0];
    const float4 bv = ((const float4*)bias)[tn];
    #pragma unroll
    for (int i = 0; i < 4; ++i) {
        const int gr = row0 + tm * 4 + i;
        float t0 = acc[i][0] + bv.x, t1 = acc[i][1] + bv.y;
        float t2 = acc[i][2] + bv.z, t3 = acc[i][3] + bv.w;
        float4 r;
        r.x = fmaxf(t0 >= 0.f ? t0 : a * t0, 0.f);
        r.y = fmaxf(t1 >= 0.f ? t1 : a * t1, 0.f);
        r.z = fmaxf(t2 >= 0.f ? t2 : a * t2, 0.f);
        r.w = fmaxf(t3 >= 0.f ? t3 : a * t3, 0.f);
        ((float4*)(out + (size_t)gr * D))[tn] = r;
    }
}

// ---------------------------------------------------------------------------
extern "C" void kernel_launch(void* const* d_in, const int* in_sizes, int n_in,
                              void* d_out, int out_size, void* d_ws, size_t ws_size,
                              hipStream_t stream) {
    const float* x    = (const float*)d_in[0];
    const int*   ei   = (const int*)d_in[1];
    const float* ew   = (const float*)d_in[2];
    const float* W    = (const float*)d_in[3];
    const float* bias = (const float*)d_in[4];
    const float* pa   = (const float*)d_in[5];
    float* out = (float*)d_out;
    int* wsb = (int*)d_ws;

    // ---- padded layout (int units) ----
    const size_t p_gcur = 0;                                  // 512
    const size_t p_off2 = 512;                                // 2*N_NODES
    const size_t p_part = p_off2 + 2 * (size_t)N_NODES;       // 200512 (even)
    const size_t p_wh   = p_part + 2 * (size_t)NCB * CAPR;    // 4,394,816 (%4==0)
    const size_t p_xh   = p_wh + (size_t)D * D / 2;           // %4==0
    const size_t needP  = (p_xh + (size_t)N_NODES * D / 2) * 4;

    // ---- compacted (fallback) layout (int units) ----
    const size_t o_ghist = 0;                                 // 512
    const size_t o_cOff  = 512;                               // 513
    const size_t o_gcur  = 1025;                              // 512
    const size_t o_off2  = 1538;                              // even; 2*N_NODES
    const size_t o_part  = o_off2 + 2 * (size_t)N_NODES;      // 201538 (even)
    const size_t o_wh    = (o_part + 2 * (size_t)N_EDGES + 3) & ~(size_t)3;
    const size_t o_xh    = o_wh + (size_t)D * D / 2;
    const size_t needA   = (o_xh + (size_t)N_NODES * D / 2) * 4;

    if (ws_size >= needP) {
        int* gcur  = wsb + p_gcur;
        int2* off2 = (int2*)(wsb + p_off2);
        int2* part = (int2*)(wsb + p_part);
        unsigned short* wh = (unsigned short*)(wsb + p_wh);
        unsigned short* xh = (unsigned short*)(wsb + p_xh);

        (void)hipMemsetAsync(gcur, 0, NCB * sizeof(int), stream);
        k_pc  <<<PBK + XQB + WQB, 256, 0, stream>>>(
            (const float4*)x, (ushort4*)xh, (const float4*)W, (ushort4*)wh,
            ei, ew, gcur, part);
        k_csrp<<<NCB, 256, 0, stream>>>(gcur, part, off2);
        k_gx  <<<N_NODES / 16, 256, 0, stream>>>(
            (const float4*)xh, off2, part, wh, bias, pa, out);
    } else if (ws_size >= needA) {
        int* ghist = wsb + o_ghist;
        int* cOff  = wsb + o_cOff;
        int* gcur  = wsb + o_gcur;
        int2* off2 = (int2*)(wsb + o_off2);
        int2* part = (int2*)(wsb + o_part);
        unsigned short* wh = (unsigned short*)(wsb + o_wh);
        unsigned short* xh = (unsigned short*)(wsb + o_xh);

        (void)hipMemsetAsync(ghist, 0, NCB * sizeof(int), stream);
        k_prep <<<HB + XQB + WQB, 256, 0, stream>>>(
            (const float4*)x, (ushort4*)xh, (const float4*)W, (ushort4*)wh, ei, ghist);
        k_cscan<<<1, NCB, 0, stream>>>(ghist, cOff, gcur);
        k_partc<<<PBK, 256, 0, stream>>>(ei, ew, gcur, part);
        k_csrc <<<NCB, 256, 0, stream>>>(cOff, part, off2);
        k_gx   <<<N_NODES / 16, 256, 0, stream>>>(
            (const float4*)xh, off2, part, wh, bias, pa, out);
    } else {
        (void)hipMemsetAsync(out, 0, (size_t)N_NODES * D * sizeof(float), stream);
        gcn_scatter<<<12800, 256, 0, stream>>>(x, ei, ew, out);
        gcn_transform<<<N_NODES / MT, 256, 0, stream>>>(out, W, bias, pa, out);
    }
}